// Round 1
// baseline (28058.929 us; speedup 1.0000x reference)
//
#include <hip/hip_runtime.h>
#include <cstdint>
#include <cstddef>

// Seq2seq LSTM, H=1024, I=1, B=512, enc T=512, dec TL=64.
// Strategy: per-step fused kernel; fp32-accurate matmul via bf16 3-term split
// (hh*wh + hl*wh + hh*wl) on mfma_f32_16x16x32_bf16; gates -> LDS -> fused
// sigmoid/tanh cell update; ping-pong bf16 h buffers between steps.

#define T_SEQ 512
#define BATCH 512
#define HDIM  1024
#define G4    4096   // 4*HDIM
#define TLEN  64

typedef __bf16 bf16x8 __attribute__((ext_vector_type(8)));
typedef float  f32x4  __attribute__((ext_vector_type(4)));

__device__ __forceinline__ unsigned short f2bf(float f) {
  unsigned u = __builtin_bit_cast(unsigned, f);
  u = u + 0x7FFFu + ((u >> 16) & 1u);          // RNE
  return (unsigned short)(u >> 16);
}
__device__ __forceinline__ float bf2f(unsigned short h) {
  return __builtin_bit_cast(float, (unsigned)h << 16);
}
__device__ __forceinline__ float sigm(float x) { return 1.0f / (1.0f + __expf(-x)); }
__device__ __forceinline__ float tanh_(float x) { return 1.0f - 2.0f / (1.0f + __expf(2.0f * x)); }

// ---------------------------------------------------------------------------
// split f32 weights -> bf16 hi + bf16 lo (residual), 4 elems/thread
__global__ __launch_bounds__(256) void split_k(const float* __restrict__ src,
                                               unsigned short* __restrict__ hi,
                                               unsigned short* __restrict__ lo, int n4) {
  int i = blockIdx.x * 256 + threadIdx.x;
  if (i >= n4) return;
  float4 f = reinterpret_cast<const float4*>(src)[i];
  ushort4 h, l;
  h.x = f2bf(f.x); l.x = f2bf(f.x - bf2f(h.x));
  h.y = f2bf(f.y); l.y = f2bf(f.y - bf2f(h.y));
  h.z = f2bf(f.z); l.z = f2bf(f.z - bf2f(h.z));
  h.w = f2bf(f.w); l.w = f2bf(f.w - bf2f(h.w));
  reinterpret_cast<ushort4*>(hi)[i] = h;
  reinterpret_cast<ushort4*>(lo)[i] = l;
}

// ---------------------------------------------------------------------------
// One LSTM step. Grid = 256 blocks (8 batch-tiles x 32 j-tiles), block = 256.
// Block tile: 64 batch rows x 32 hidden cols -> 128 gate cols (4 gates x 32).
// Gate col c in [0,128): gate g = c>>5, jj = c&31, Whh row = g*1024 + j0 + jj.
// Wave grid 2x2: each wave = 2 M-tiles (16 rows) x 4 N-tiles (16 cols).
__global__ __launch_bounds__(256, 1) void lstm_step(
    const float* __restrict__ xv,          // [BATCH] scalar input per batch row
    const float* __restrict__ Wih,         // [G4]
    const float* __restrict__ bias,        // [G4]
    const unsigned short* __restrict__ w_hi,  // [G4][HDIM] bf16
    const unsigned short* __restrict__ w_lo,
    const unsigned short* __restrict__ hh_in, // [BATCH][HDIM] bf16
    const unsigned short* __restrict__ hl_in,
    unsigned short* __restrict__ hh_out,
    unsigned short* __restrict__ hl_out,
    float* __restrict__ c,                 // [BATCH][HDIM]
    float* __restrict__ hf)                // [BATCH][HDIM] f32 h (for projection)
{
  const int tid  = threadIdx.x;
  const int lane = tid & 63;
  const int wid  = tid >> 6;
  const int l15  = lane & 15;
  const int lk   = lane >> 4;      // k-group 0..3

  // XCD-aware decode: blockIdx % 8 = XCD; each XCD owns 4 consecutive j-tiles
  const int xcd  = blockIdx.x & 7;
  const int slot = blockIdx.x >> 3;
  const int jb   = xcd * 4 + (slot & 3);   // 0..31
  const int bb   = slot >> 2;              // 0..7
  const int rbase = bb * 64;
  const int j0    = jb * 32;

  const int wr = wid >> 1;   // 0..1 wave row
  const int wc = wid & 1;    // 0..1 wave col

  // B-fragment base pointers (4 N-tiles per wave)
  const unsigned short* pbh[4];
  const unsigned short* pbl[4];
#pragma unroll
  for (int n = 0; n < 4; ++n) {
    int cc = wc * 64 + n * 16 + l15;       // gate col 0..127
    int g  = cc >> 5;
    int jj = cc & 31;
    size_t off = (size_t)(g * HDIM + j0 + jj) * HDIM + (size_t)lk * 8;
    pbh[n] = w_hi + off;
    pbl[n] = w_lo + off;
  }
  // A-fragment base pointers (2 M-tiles per wave)
  const unsigned short* pah[2];
  const unsigned short* pal[2];
#pragma unroll
  for (int m = 0; m < 2; ++m) {
    int row = rbase + wr * 32 + m * 16 + l15;
    size_t off = (size_t)row * HDIM + (size_t)lk * 8;
    pah[m] = hh_in + off;
    pal[m] = hl_in + off;
  }

  f32x4 acc[2][4] = {};

  for (int k = 0; k < HDIM; k += 32) {
    bf16x8 ah[2], al[2], bh[4], bl[4];
#pragma unroll
    for (int m = 0; m < 2; ++m) {
      ah[m] = *reinterpret_cast<const bf16x8*>(pah[m] + k);
      al[m] = *reinterpret_cast<const bf16x8*>(pal[m] + k);
    }
#pragma unroll
    for (int n = 0; n < 4; ++n) {
      bh[n] = *reinterpret_cast<const bf16x8*>(pbh[n] + k);
      bl[n] = *reinterpret_cast<const bf16x8*>(pbl[n] + k);
    }
#pragma unroll
    for (int m = 0; m < 2; ++m)
#pragma unroll
      for (int n = 0; n < 4; ++n) {
        acc[m][n] = __builtin_amdgcn_mfma_f32_16x16x32_bf16(ah[m], bh[n], acc[m][n], 0, 0, 0);
        acc[m][n] = __builtin_amdgcn_mfma_f32_16x16x32_bf16(al[m], bh[n], acc[m][n], 0, 0, 0);
        acc[m][n] = __builtin_amdgcn_mfma_f32_16x16x32_bf16(ah[m], bl[n], acc[m][n], 0, 0, 0);
      }
  }

  // C/D layout (m89-verified): lane holds D[(lane>>4)*4 + r][lane&15]
  __shared__ float lds[64][129];
#pragma unroll
  for (int m = 0; m < 2; ++m)
#pragma unroll
    for (int n = 0; n < 4; ++n)
#pragma unroll
      for (int r = 0; r < 4; ++r)
        lds[wr * 32 + m * 16 + lk * 4 + r][wc * 64 + n * 16 + l15] = acc[m][n][r];
  __syncthreads();

  // Epilogue: 64 rows x 32 j per block = 2048 cells, 8 per thread
#pragma unroll
  for (int it = 0; it < 8; ++it) {
    int idx = tid + it * 256;
    int row = idx >> 5;
    int jj  = idx & 31;
    int bglob = rbase + row;
    int jcol  = j0 + jj;
    float xs = xv[bglob];
    float gi = lds[row][jj]      + xs * Wih[jcol]            + bias[jcol];
    float gf = lds[row][32 + jj] + xs * Wih[HDIM + jcol]     + bias[HDIM + jcol];
    float gg = lds[row][64 + jj] + xs * Wih[2 * HDIM + jcol] + bias[2 * HDIM + jcol];
    float go = lds[row][96 + jj] + xs * Wih[3 * HDIM + jcol] + bias[3 * HDIM + jcol];
    size_t p = (size_t)bglob * HDIM + jcol;
    float cn = sigm(gf) * c[p] + sigm(gi) * tanh_(gg);
    c[p] = cn;
    float hn = sigm(go) * tanh_(cn);
    hf[p] = hn;
    unsigned short hh_ = f2bf(hn);
    hh_out[p] = hh_;
    hl_out[p] = f2bf(hn - bf2f(hh_));
  }
}

// ---------------------------------------------------------------------------
// y[b] = dot(h[b,:], linW) + linb ; one wave per batch row
__global__ __launch_bounds__(256) void proj_k(const float* __restrict__ hf,
                                              const float* __restrict__ linW,
                                              const float* __restrict__ linb,
                                              float* __restrict__ y) {
  int wid  = threadIdx.x >> 6;
  int lane = threadIdx.x & 63;
  int row  = blockIdx.x * 4 + wid;
  const float4* hp = reinterpret_cast<const float4*>(hf + (size_t)row * HDIM);
  const float4* wp = reinterpret_cast<const float4*>(linW);
  float s = 0.0f;
#pragma unroll
  for (int it = 0; it < 4; ++it) {
    int j = it * 64 + lane;
    float4 a = hp[j], w = wp[j];
    s += a.x * w.x + a.y * w.y + a.z * w.z + a.w * w.w;
  }
#pragma unroll
  for (int off = 32; off > 0; off >>= 1) s += __shfl_down(s, off);
  if (lane == 0) y[row] = s + linb[0];
}

// ---------------------------------------------------------------------------
extern "C" void kernel_launch(void* const* d_in, const int* in_sizes, int n_in,
                              void* d_out, int out_size, void* d_ws, size_t ws_size,
                              hipStream_t stream) {
  const float* x       = (const float*)d_in[0];   // [512,512,1]
  const float* enc_Wih = (const float*)d_in[1];   // [4096,1]
  const float* enc_Whh = (const float*)d_in[2];   // [4096,1024]
  const float* enc_b   = (const float*)d_in[3];   // [4096]
  const float* dec_Wih = (const float*)d_in[4];
  const float* dec_Whh = (const float*)d_in[5];
  const float* dec_b   = (const float*)d_in[6];
  const float* lin_W   = (const float*)d_in[7];   // [1,1024]
  const float* lin_b   = (const float*)d_in[8];   // [1]
  float* out = (float*)d_out;                     // [64,512,1]

  uint8_t* w = (uint8_t*)d_ws;
  const size_t MB = 1u << 20;
  float*          c_ptr = (float*)(w + 0 * MB);           // 2 MB
  float*          hf    = (float*)(w + 2 * MB);           // 2 MB
  unsigned short* hh[2] = { (unsigned short*)(w + 4 * MB), (unsigned short*)(w + 5 * MB) };
  unsigned short* hl[2] = { (unsigned short*)(w + 6 * MB), (unsigned short*)(w + 7 * MB) };
  unsigned short* enc_hi = (unsigned short*)(w + 8 * MB);   // 8 MB each
  unsigned short* enc_lo = (unsigned short*)(w + 16 * MB);
  unsigned short* dec_hi = (unsigned short*)(w + 24 * MB);
  unsigned short* dec_lo = (unsigned short*)(w + 32 * MB);  // total 40 MB

  // zero c, hf, h ping-pong buffers
  hipMemsetAsync(d_ws, 0, 8 * MB, stream);

  const int n4 = G4 * HDIM / 4;
  split_k<<<(n4 + 255) / 256, 256, 0, stream>>>(enc_Whh, enc_hi, enc_lo, n4);
  split_k<<<(n4 + 255) / 256, 256, 0, stream>>>(dec_Whh, dec_hi, dec_lo, n4);

  // encoder
  for (int t = 0; t < T_SEQ; ++t) {
    int p = t & 1;
    lstm_step<<<256, 256, 0, stream>>>(x + (size_t)t * BATCH, enc_Wih, enc_b,
                                       enc_hi, enc_lo,
                                       hh[p], hl[p], hh[p ^ 1], hl[p ^ 1],
                                       c_ptr, hf);
  }
  // decoder (feeds its own scalar output back)
  for (int t = 0; t < TLEN; ++t) {
    int p = t & 1;
    const float* xin = (t == 0) ? (x + (size_t)(T_SEQ - 1) * BATCH)
                                : (out + (size_t)(t - 1) * BATCH);
    lstm_step<<<256, 256, 0, stream>>>(xin, dec_Wih, dec_b,
                                       dec_hi, dec_lo,
                                       hh[p], hl[p], hh[p ^ 1], hl[p ^ 1],
                                       c_ptr, hf);
    proj_k<<<128, 256, 0, stream>>>(hf, lin_W, lin_b, out + (size_t)t * BATCH);
  }
  (void)in_sizes; (void)n_in; (void)out_size; (void)ws_size;
}

// Round 4
// 11791.699 us; speedup vs baseline: 2.3795x; 2.3795x over previous
//
#include <hip/hip_runtime.h>
#include <cstdint>
#include <cstddef>

// Seq2seq LSTM, H=1024, I=1, B=512, enc T=512, dec TL=64.
// Per-step fused kernel. gates = h @ W^T computed as bf16 MFMA with
// 2-term weight split (w_hi + w_lo), h quantized to bf16 per step.
// Decoder scalar feedback folded into weights via rank-1 update.

#define HD    1024
#define G4    4096
#define NSTEP 576            // 512 enc + 64 dec
#define TLEN  64

typedef __bf16 bf16x8 __attribute__((ext_vector_type(8)));
typedef float  f32x4  __attribute__((ext_vector_type(4)));
typedef __attribute__((address_space(1))) const unsigned int glob_u32;
typedef __attribute__((address_space(3))) unsigned int lds_u32;

__device__ __forceinline__ unsigned short f2bf(float f) {
  unsigned u = __builtin_bit_cast(unsigned, f);
  u = u + 0x7FFFu + ((u >> 16) & 1u);          // RNE
  return (unsigned short)(u >> 16);
}
__device__ __forceinline__ float bf2f(unsigned short h) {
  return __builtin_bit_cast(float, (unsigned)h << 16);
}
__device__ __forceinline__ float sigm(float x) { return 1.0f / (1.0f + __expf(-x)); }
__device__ __forceinline__ float tanh_(float x) { return 1.0f - 2.0f / (1.0f + __expf(2.0f * x)); }

// ---------------------------------------------------------------------------
// Repack Whh (optionally + Wih*linW rank-1) into per-tile swizzled bf16 hi/lo.
// dst[tile][dt][c][k ^ ((c&7)<<3)], tile=j>>3, c=g*8+(j&7), 65536 elems/tile.
__global__ __launch_bounds__(256) void prep_w(const float* __restrict__ Whh,
                                              const float* __restrict__ Wih,
                                              const float* __restrict__ linW,
                                              int fold,
                                              unsigned short* __restrict__ dst) {
  int gid  = blockIdx.x * 256 + threadIdx.x;   // 0 .. 1048575
  int rowg = gid >> 8;                          // 0..4095
  int k0   = (gid & 255) << 2;                  // 0..1020
  float4 wv = *reinterpret_cast<const float4*>(Whh + (size_t)rowg * HD + k0);
  if (fold) {
    float wi = Wih[rowg];
    float4 lw = *reinterpret_cast<const float4*>(linW + k0);
    wv.x += wi * lw.x; wv.y += wi * lw.y; wv.z += wi * lw.z; wv.w += wi * lw.w;
  }
  ushort4 hi, lo;
  hi.x = f2bf(wv.x); lo.x = f2bf(wv.x - bf2f(hi.x));
  hi.y = f2bf(wv.y); lo.y = f2bf(wv.y - bf2f(hi.y));
  hi.z = f2bf(wv.z); lo.z = f2bf(wv.z - bf2f(hi.z));
  hi.w = f2bf(wv.w); lo.w = f2bf(wv.w - bf2f(hi.w));
  int g = rowg >> 10, j = rowg & 1023;
  int tile = j >> 3, c = g * 8 + (j & 7);
  size_t base = (size_t)tile * 65536 + (size_t)c * 1024 + (size_t)(k0 ^ ((c & 7) << 3));
  *reinterpret_cast<ushort4*>(dst + base)         = hi;   // dt=0
  *reinterpret_cast<ushort4*>(dst + base + 32768) = lo;   // dt=1
}

__global__ __launch_bounds__(256) void init_out(float* __restrict__ out,
                                                const float* __restrict__ lin_b) {
  int i = blockIdx.x * 256 + threadIdx.x;
  if (i < TLEN * 512) out[i] = lin_b[0];
}

// ---------------------------------------------------------------------------
// One LSTM step. Grid 256 x 512 threads. Block = (rh: 256 batch rows) x
// (tile: 8 hidden j -> 32 gate cols). Weights staged to LDS (pre-swizzled).
// h read from hT[kblk][row][32] (coalesced), written back bf16.
__global__ __launch_bounds__(512, 1) void lstm_step(
    const float* __restrict__ xv,      // per-row input (or null)
    const float* __restrict__ psub,    // subtract h_enc.linW (dec step 0 only)
    const float* __restrict__ xcp,     // scalar add, broadcast (lin_b) or null
    const float* __restrict__ Wih,     // [4096]
    const float* __restrict__ bias,    // [4096]
    const float* __restrict__ linW,    // [1024]
    const unsigned short* __restrict__ wbuf,   // [128][2][32][1024] swizzled
    const unsigned short* __restrict__ hT_in,  // [32][512][32] bf16
    unsigned short* __restrict__ hT_out,
    float* __restrict__ c_buf,                 // [128][2][256][8]
    float* __restrict__ yout)                  // atomic target (p or out row) or null
{
  __shared__ __align__(16) unsigned char smem[131072 + 512];
  const int tid  = threadIdx.x;
  const int lane = tid & 63;
  const int wid  = tid >> 6;           // 0..7
  const int l15  = lane & 15;
  const int lk   = lane >> 4;          // 0..3

  const int bid  = blockIdx.x;
  const int rh   = (bid >> 2) & 1;                 // XCDs 0-3 -> rh0, 4-7 -> rh1
  const int tile = (bid >> 3) * 4 + (bid & 3);     // 0..127

  // ---- stage 128 KB of weights: global (pre-swizzled) -> LDS linear
  {
    glob_u32* g = (glob_u32*)(wbuf + (size_t)tile * 65536);
    lds_u32*  l = (lds_u32*)smem;
#pragma unroll
    for (int i = 0; i < 16; ++i)
      __builtin_amdgcn_global_load_lds(g + i * 2048 + tid * 4,
                                       l + i * 2048 + tid * 4, 16, 0, 0);
  }
  float* wihs = (float*)(smem + 131072);
  float* bs   = (float*)(smem + 131072 + 128);
  float* lws  = (float*)(smem + 131072 + 256);
  if (tid < 32) {
    int g = tid >> 3, jj = tid & 7;
    int r = g * HD + tile * 8 + jj;
    wihs[tid] = Wih[r];
    bs[tid]   = bias[r];
  } else if (tid < 40) {
    lws[tid - 32] = linW[tile * 8 + (tid - 32)];
  }
  __syncthreads();

  // ---- MFMA: wave wid owns rows [wid*32, wid*32+32), all 32 cols (2m x 2n)
  const int rowbase = rh * 256 + wid * 32;
  const unsigned short* pa[2];
#pragma unroll
  for (int m = 0; m < 2; ++m)
    pa[m] = hT_in + (size_t)(rowbase + m * 16 + l15) * 32 + lk * 8;

  int QH[2], QL[2];                       // LDS byte offsets (lane-const part)
#pragma unroll
  for (int nt = 0; nt < 2; ++nt) {
    int c = nt * 16 + l15;
    int s = (c & 7) << 4;
    int q = c * 2048 + ((lk * 16) ^ s);   // bits disjoint: + == ^
    QH[nt] = q;
    QL[nt] = 65536 + q;
  }

  f32x4 acc[2][2] = {};
  bf16x8 Af[3][2], BH[2][2], BL[2][2];

#define LOADA(kk, st)                                                        \
  { _Pragma("unroll") for (int m = 0; m < 2; ++m)                            \
      Af[st][m] = *(const bf16x8*)(pa[m] + (size_t)(kk) * 16384); }
#define LOADB(kk, st)                                                        \
  { _Pragma("unroll") for (int nt = 0; nt < 2; ++nt) {                       \
      BH[st][nt] = *(const bf16x8*)(smem + (QH[nt] ^ ((kk) << 6)));          \
      BL[st][nt] = *(const bf16x8*)(smem + (QL[nt] ^ ((kk) << 6))); } }

  LOADA(0, 0); LOADA(1, 1); LOADB(0, 0);
#pragma unroll
  for (int kk = 0; kk < 32; ++kk) {
    if (kk + 2 < 32) LOADA(kk + 2, (kk + 2) % 3);
    if (kk + 1 < 32) LOADB(kk + 1, (kk + 1) & 1);
#pragma unroll
    for (int m = 0; m < 2; ++m)
#pragma unroll
      for (int nt = 0; nt < 2; ++nt) {
        acc[m][nt] = __builtin_amdgcn_mfma_f32_16x16x32_bf16(
            Af[kk % 3][m], BH[kk & 1][nt], acc[m][nt], 0, 0, 0);
        acc[m][nt] = __builtin_amdgcn_mfma_f32_16x16x32_bf16(
            Af[kk % 3][m], BL[kk & 1][nt], acc[m][nt], 0, 0, 0);
      }
  }
#undef LOADA
#undef LOADB

  // ---- gates -> LDS (overlay weight region; all reads done)
  __syncthreads();
  float* gl = (float*)smem;               // [256][33]
#pragma unroll
  for (int m = 0; m < 2; ++m)
#pragma unroll
    for (int nt = 0; nt < 2; ++nt)
#pragma unroll
      for (int r = 0; r < 4; ++r)
        gl[(wid * 32 + m * 16 + lk * 4 + r) * 33 + nt * 16 + l15] = acc[m][nt][r];
  __syncthreads();

  // ---- cell update: thread -> (row = tid>>1, half jp = tid&1 -> 4 j's)
  const int row  = tid >> 1;
  const int jp   = tid & 1;
  const int grow = rh * 256 + row;
  float xs = 0.0f;
  if (xv)   xs += xv[grow];
  if (psub) xs -= psub[grow];
  if (xcp)  xs += xcp[0];

  float* cp = c_buf + (size_t)tile * 4096 + rh * 2048 + row * 8 + jp * 4;
  float4 cold = *reinterpret_cast<const float4*>(cp);
  float4 cnew;
  ushort4 hw;
  float ypart = 0.0f;
#pragma unroll
  for (int q = 0; q < 4; ++q) {
    int jj = jp * 4 + q;
    float gi = gl[row * 33 + jj]      + xs * wihs[jj]      + bs[jj];
    float gf = gl[row * 33 + 8 + jj]  + xs * wihs[8 + jj]  + bs[8 + jj];
    float gg = gl[row * 33 + 16 + jj] + xs * wihs[16 + jj] + bs[16 + jj];
    float go = gl[row * 33 + 24 + jj] + xs * wihs[24 + jj] + bs[24 + jj];
    float cv = (&cold.x)[q];
    float cn = sigm(gf) * cv + sigm(gi) * tanh_(gg);
    float hn = sigm(go) * tanh_(cn);
    (&cnew.x)[q] = cn;
    ypart += hn * lws[jj];
    ((unsigned short*)&hw)[q] = f2bf(hn);
  }
  *reinterpret_cast<float4*>(cp) = cnew;
  const int kblk = tile >> 2;
  const int keb  = (tile & 3) * 8;
  *reinterpret_cast<ushort4*>(hT_out + (size_t)kblk * 16384 + (size_t)grow * 32
                              + keb + jp * 4) = hw;
  if (yout) {
    ypart += __shfl_xor(ypart, 1);
    if ((lane & 1) == 0) atomicAdd(yout + grow, ypart);
  }
}

// ---------------------------------------------------------------------------
extern "C" void kernel_launch(void* const* d_in, const int* in_sizes, int n_in,
                              void* d_out, int out_size, void* d_ws, size_t ws_size,
                              hipStream_t stream) {
  const float* x       = (const float*)d_in[0];   // [512,512,1]
  const float* enc_Wih = (const float*)d_in[1];
  const float* enc_Whh = (const float*)d_in[2];
  const float* enc_b   = (const float*)d_in[3];
  const float* dec_Wih = (const float*)d_in[4];
  const float* dec_Whh = (const float*)d_in[5];
  const float* dec_b   = (const float*)d_in[6];
  const float* lin_W   = (const float*)d_in[7];   // [1,1024]
  const float* lin_b   = (const float*)d_in[8];   // [1]
  float* out = (float*)d_out;                     // [64,512]

  uint8_t* w = (uint8_t*)d_ws;
  const size_t MB = 1u << 20;
  float*          c_buf = (float*)(w + 0 * MB);            // 2 MB
  unsigned short* hT0   = (unsigned short*)(w + 2 * MB);   // 1 MB
  float*          p     = (float*)(w + 3 * MB);            // 2 KB
  unsigned short* hT1   = (unsigned short*)(w + 4 * MB);   // 1 MB
  unsigned short* wenc  = (unsigned short*)(w + 8 * MB);   // 16 MB
  unsigned short* wdec  = (unsigned short*)(w + 24 * MB);  // 16 MB (total 40)
  unsigned short* hT[2] = { hT0, hT1 };

  // zero c (2MB) + hT0 (1MB) + p
  hipMemsetAsync(d_ws, 0, 3 * MB + 4096, stream);
  init_out<<<128, 256, 0, stream>>>(out, lin_b);
  prep_w<<<4096, 256, 0, stream>>>(enc_Whh, enc_Wih, lin_W, 0, wenc);
  prep_w<<<4096, 256, 0, stream>>>(dec_Whh, dec_Wih, lin_W, 1, wdec);

  for (int t = 0; t < NSTEP; ++t) {
    const unsigned short* hin = hT[t & 1];
    unsigned short* hout      = hT[(t + 1) & 1];
    if (t < 512) {            // encoder
      lstm_step<<<256, 512, 0, stream>>>(
          x + (size_t)t * 512, nullptr, nullptr,
          enc_Wih, enc_b, lin_W, wenc, hin, hout, c_buf,
          (t == 511) ? p : nullptr);
    } else if (t == 512) {    // decoder step 0: input = x[-1]
      lstm_step<<<256, 512, 0, stream>>>(
          x + (size_t)511 * 512, p, nullptr,
          dec_Wih, dec_b, lin_W, wdec, hin, hout, c_buf, out);
    } else {                  // decoder steps 1..63: feedback folded, xs = lin_b
      int s = t - 512;
      lstm_step<<<256, 512, 0, stream>>>(
          nullptr, nullptr, lin_b,
          dec_Wih, dec_b, lin_W, wdec, hin, hout, c_buf,
          out + (size_t)s * 512);
    }
  }
  (void)in_sizes; (void)n_in; (void)out_size; (void)ws_size;
}